// Round 4
// baseline (105.785 us; speedup 1.0000x reference)
//
#include <hip/hip_runtime.h>

// Focal loss (adaptive gamma) forward, sum-reduced.
// input: [N, C] float32, target: [N] int32, out: scalar float32.
// Harness: N=32768, C=4096. Kernel assumes C == 4096.
//
// R4: persistent-wave row kernel (1024 blocks x 4 waves, 8 rows/wave,
// 16x float4 in registers, no LDS/barriers in hot loop) + tiny reduce
// kernel over 1024 per-block partials. No cooperative launch (R3 showed
// hipLaunchCooperativeKernel fails under the harness's graph capture).

#define CCONST 4096
#define THREADS 256
#define WAVES_PER_BLOCK 4
#define BLOCKS 1024                               // 4 blocks/CU on 256 CUs
#define TOTAL_WAVES (BLOCKS * WAVES_PER_BLOCK)    // 4096 waves

#define LOG2E 1.44269504088896340736f

__global__ __launch_bounds__(THREADS, 4) void focal_row_kernel(
    const float* __restrict__ inp,
    const int* __restrict__ target,
    float* __restrict__ partial,      // [BLOCKS]
    int n_rows)
{
    const int lane = threadIdx.x & 63;
    const int wave = threadIdx.x >> 6;
    const int wave_global = blockIdx.x * WAVES_PER_BLOCK + wave;

    const int rows_per_wave = (n_rows + TOTAL_WAVES - 1) / TOTAL_WAVES;  // 8
    const int row0 = wave_global * rows_per_wave;

    float loss_acc = 0.0f;

    for (int r = 0; r < rows_per_wave; ++r) {
        const int row = row0 + r;
        if (row >= n_rows) break;

        // Wave-uniform gather (broadcast transaction); latency hidden under
        // the 16 bulk loads issued right after.
        const int c = target[row];
        const float xt = inp[(size_t)row * CCONST + c];

        const float4* rowp = reinterpret_cast<const float4*>(inp + (size_t)row * CCONST);
        float4 v[16];
#pragma unroll
        for (int k = 0; k < 16; ++k)
            v[k] = rowp[lane + 64 * k];

        // --- row max (v_max3-friendly tree, then 6-step butterfly) ---
        float m = -INFINITY;
#pragma unroll
        for (int k = 0; k < 16; ++k)
            m = fmaxf(m, fmaxf(fmaxf(v[k].x, v[k].y), fmaxf(v[k].z, v[k].w)));
#pragma unroll
        for (int off = 32; off > 0; off >>= 1)
            m = fmaxf(m, __shfl_xor(m, off));

        // --- sum exp(x - m) = exp2(x*log2e - m*log2e): one FMA + v_exp each
        const float mk = -m * LOG2E;
        float s = 0.0f;
#pragma unroll
        for (int k = 0; k < 16; ++k) {
            s += exp2f(fmaf(v[k].x, LOG2E, mk)) + exp2f(fmaf(v[k].y, LOG2E, mk))
               + exp2f(fmaf(v[k].z, LOG2E, mk)) + exp2f(fmaf(v[k].w, LOG2E, mk));
        }
#pragma unroll
        for (int off = 32; off > 0; off >>= 1)
            s += __shfl_xor(s, off);

        // m, s, xt wave-uniform: all lanes compute identically (no divergence).
        float logpt = xt - m - __logf(s);
        float pt = __expf(logpt);
        float u = 1.0f - pt;
        float w;
        if (pt >= 0.5f) {
            w = 1.0f;                    // gamma = 0
        } else if (pt < 0.2f) {
            float u2 = u * u;            // gamma = 5
            w = u2 * u2 * u;
        } else {
            w = u * u * u;               // gamma = 3
        }
        loss_acc += -w * logpt;
    }

    // Per-block partial (loss_acc wave-uniform; lane 0 of each wave).
    __shared__ float ls[WAVES_PER_BLOCK];
    if (lane == 0) ls[wave] = loss_acc;
    __syncthreads();
    if (threadIdx.x == 0)
        partial[blockIdx.x] = (ls[0] + ls[1]) + (ls[2] + ls[3]);
}

// Deterministic fixed-tree reduction of BLOCKS partials -> scalar.
__global__ __launch_bounds__(THREADS) void focal_reduce_kernel(
    const float* __restrict__ partial,
    float* __restrict__ out)
{
    const int t = threadIdx.x;
    float s = 0.0f;
#pragma unroll
    for (int i = 0; i < BLOCKS / THREADS; ++i)
        s += partial[t + THREADS * i];

#pragma unroll
    for (int off = 32; off > 0; off >>= 1)
        s += __shfl_xor(s, off);

    __shared__ float ssum[THREADS / 64];
    if ((t & 63) == 0) ssum[t >> 6] = s;
    __syncthreads();
    if (t == 0)
        out[0] = (ssum[0] + ssum[1]) + (ssum[2] + ssum[3]);
}

extern "C" void kernel_launch(void* const* d_in, const int* in_sizes, int n_in,
                              void* d_out, int out_size, void* d_ws, size_t ws_size,
                              hipStream_t stream)
{
    const float* inp    = (const float*)d_in[0];
    const int*   target = (const int*)d_in[1];
    float* out = (float*)d_out;
    float* partial = (float*)d_ws;      // BLOCKS floats of scratch

    const int N = in_sizes[1];          // 32768

    focal_row_kernel<<<BLOCKS, THREADS, 0, stream>>>(inp, target, partial, N);
    focal_reduce_kernel<<<1, THREADS, 0, stream>>>(partial, out);
}

// Round 6
// 85.674 us; speedup vs baseline: 1.2347x; 1.2347x over previous
//
#include <hip/hip_runtime.h>

// Focal loss (adaptive gamma) forward, sum-reduced.
// input: [N, C] float32, target: [N] int32, out: scalar float32.
// Harness: N=32768, C=4096. Kernel assumes C == 4096.
//
// R6 = R5 with the nontemporal-load type fixed (clang ext_vector_type,
// HIP_vector_type is rejected by __builtin_nontemporal_load).
// Two waves per row (128 threads/row, 8x float4 per lane -> ~56 VGPRs
// -> ~8 waves/SIMD resident) to smooth the load-burst/compute-bubble
// alternation. Nontemporal bulk loads (read-once stream). Cross-wave
// reductions via tiny LDS. Block partials -> small reduce kernel.

#define CCONST 4096
#define THREADS 256
#define ROWS_PER_BLOCK 2            // 2 waves per row
#define LOG2E 1.44269504088896340736f

typedef float f32x4 __attribute__((ext_vector_type(4)));

__global__ __launch_bounds__(THREADS) void focal_row_kernel(
    const float* __restrict__ inp,
    const int* __restrict__ target,
    float* __restrict__ partial,      // [gridDim.x]
    int n_rows)
{
    const int t     = threadIdx.x;
    const int lane  = t & 63;
    const int wave  = t >> 6;         // 0..3
    const int rhalf = wave & 1;       // which half of the row this wave reads
    const int rloc  = wave >> 1;      // row index within block (0..1)
    const int row   = blockIdx.x * ROWS_PER_BLOCK + rloc;

    __shared__ float sm[4];           // per-wave max
    __shared__ float ss[4];           // per-wave expsum
    __shared__ float lsum[ROWS_PER_BLOCK];

    float loss = 0.0f;
    if (row < n_rows) {
        const float* rowbase = inp + (size_t)row * CCONST;

        // Wave-uniform target gather first (normal, cacheable load).
        const int c = target[row];
        const float xt = rowbase[c];

        // Half-row bulk load: 8x float4 per lane, nontemporal (read-once).
        const f32x4* rowp = reinterpret_cast<const f32x4*>(rowbase) + rhalf * 512;
        f32x4 v[8];
#pragma unroll
        for (int k = 0; k < 8; ++k)
            v[k] = __builtin_nontemporal_load(&rowp[lane + 64 * k]);

        // --- local max over 32 elems, then 6-step butterfly ---
        float m = -INFINITY;
#pragma unroll
        for (int k = 0; k < 8; ++k)
            m = fmaxf(m, fmaxf(fmaxf(v[k].x, v[k].y), fmaxf(v[k].z, v[k].w)));
#pragma unroll
        for (int off = 32; off > 0; off >>= 1)
            m = fmaxf(m, __shfl_xor(m, off));

        if (lane == 0) sm[wave] = m;
        __syncthreads();
        m = fmaxf(sm[rloc * 2], sm[rloc * 2 + 1]);   // row max

        // --- sum exp(x-m) = exp2(x*log2e - m*log2e): one FMA + v_exp each ---
        const float mk = -m * LOG2E;
        float s = 0.0f;
#pragma unroll
        for (int k = 0; k < 8; ++k) {
            s += exp2f(fmaf(v[k].x, LOG2E, mk)) + exp2f(fmaf(v[k].y, LOG2E, mk))
               + exp2f(fmaf(v[k].z, LOG2E, mk)) + exp2f(fmaf(v[k].w, LOG2E, mk));
        }
#pragma unroll
        for (int off = 32; off > 0; off >>= 1)
            s += __shfl_xor(s, off);

        if (lane == 0) ss[wave] = s;
        __syncthreads();
        s = ss[rloc * 2] + ss[rloc * 2 + 1];          // row expsum

        // Uniform across the row's waves; compute on all lanes.
        float logpt = xt - m - __logf(s);
        float pt = __expf(logpt);
        float u = 1.0f - pt;
        float w;
        if (pt >= 0.5f) {
            w = 1.0f;                    // gamma = 0
        } else if (pt < 0.2f) {
            float u2 = u * u;            // gamma = 5
            w = u2 * u2 * u;
        } else {
            w = u * u * u;               // gamma = 3
        }
        loss = -w * logpt;
    } else {
        __syncthreads();
        __syncthreads();
    }

    // One value per row (waves 0 and 2 hold rows 0 and 1).
    if ((wave & 1) == 0 && lane == 0) lsum[rloc] = loss;
    __syncthreads();
    if (t == 0)
        partial[blockIdx.x] = lsum[0] + lsum[1];
}

// Deterministic fixed-tree reduction of block partials -> scalar.
#define RED_THREADS 1024
__global__ __launch_bounds__(RED_THREADS) void focal_reduce_kernel(
    const float* __restrict__ partial,
    float* __restrict__ out,
    int n)
{
    const int t = threadIdx.x;
    float s = 0.0f;
#pragma unroll 4
    for (int i = t; i < n; i += RED_THREADS)
        s += partial[i];

#pragma unroll
    for (int off = 32; off > 0; off >>= 1)
        s += __shfl_xor(s, off);

    __shared__ float ssum[RED_THREADS / 64];
    if ((t & 63) == 0) ssum[t >> 6] = s;
    __syncthreads();
    if (t == 0) {
        float tot = 0.0f;
#pragma unroll
        for (int i = 0; i < RED_THREADS / 64; ++i)
            tot += ssum[i];
        out[0] = tot;
    }
}

extern "C" void kernel_launch(void* const* d_in, const int* in_sizes, int n_in,
                              void* d_out, int out_size, void* d_ws, size_t ws_size,
                              hipStream_t stream)
{
    const float* inp    = (const float*)d_in[0];
    const int*   target = (const int*)d_in[1];
    float* out = (float*)d_out;
    float* partial = (float*)d_ws;      // one float per block

    const int N = in_sizes[1];          // 32768
    const int blocks = (N + ROWS_PER_BLOCK - 1) / ROWS_PER_BLOCK;   // 16384

    focal_row_kernel<<<blocks, THREADS, 0, stream>>>(inp, target, partial, N);
    focal_reduce_kernel<<<1, RED_THREADS, 0, stream>>>(partial, out, blocks);
}